// Round 7
// baseline (58.600 us; speedup 1.0000x reference)
//
#include <hip/hip_runtime.h>
#include <hip/hip_bf16.h>
#include <stdint.h>

#define B_ 2
#define N_ 3000
#define F_ 64
#define H_ 4
#define D_ 32
#define K_ 128          // H_*D_ output feature cols
#define KT_ 9           // 9 k-tiles of 16 -> 144 cols (128 feat + 4 denom + 12 pad)
#define NCH_ 94         // ceil(3000/32) m-chunks (3008 padded)
#define NROWT_ 188      // ceil(3000/16) row tiles per batch
#define S_ 8            // split-K factor (blocks per row-tile)
#define PT_ 2304        // partial tile floats: 36 x 64
#define CHB_ 9216       // bytes per G chunk (9 tiles x 64 lanes x 16B)

typedef short bf16x8 __attribute__((ext_vector_type(8)));
typedef float f32x4  __attribute__((ext_vector_type(4)));

__device__ __forceinline__ unsigned short f2bf(float f) {
    uint32_t x = __float_as_uint(f);
    return (unsigned short)((x + 0x7FFFu + ((x >> 16) & 1u)) >> 16);  // RNE
}

// ---- Pass 1: feat[b][h][n][d] = h . kernel ; e2[b][h][n] = feat . att_k2 ; node_mask
__global__ void k_feat(const float* __restrict__ hin, const float* __restrict__ kern,
                       const float* __restrict__ ak2,
                       float* __restrict__ feat, float* __restrict__ e2,
                       float* __restrict__ nmask) {
    int b = blockIdx.x / N_;
    int n = blockIdx.x % N_;
    __shared__ float hrow[F_];
    int tid = threadIdx.x;                       // 128 threads: (h = tid>>5, d = tid&31)
    if (tid < F_) hrow[tid] = hin[(size_t)(b * N_ + n) * F_ + tid];
    __syncthreads();
    int hh = tid >> 5, d = tid & 31;
    float acc = 0.f;
    #pragma unroll
    for (int f = 0; f < F_; ++f)
        acc = fmaf(hrow[f], kern[(hh * F_ + f) * D_ + d], acc);
    feat[((size_t)(b * H_ + hh) * N_ + n) * D_ + d] = acc;
    float v = acc * ak2[hh * D_ + d];
    #pragma unroll
    for (int o = 16; o >= 1; o >>= 1) v += __shfl_xor(v, o, 32);
    if (d == 0) e2[(size_t)(b * H_ + hh) * N_ + n] = v;
    unsigned long long bal = __ballot(tid < F_ && hrow[tid & (F_ - 1)] != 0.0f);
    if (tid == 0) nmask[b * N_ + n] = (bal != 0ull) ? 1.0f : 0.0f;
}

// ---- Pass 2: G in MFMA-B-fragment order: G[((b*94+ch)*9+t)*64 + lane] = ushort8
//      lane: rg=lane>>4, col=lane&15 ; element j -> Gmat[m = ch*32+rg*8+j][k = t*16+col]
//      Gmat[m][k<128] = w[h][m]*feat[h][m][d] (h=k>>5,d=k&31); k in 128..131 -> w[k-128][m]; else 0
//      w[h][m] = exp(e2[h][m])  (max-subtraction cancels in the ratio; |e2|~O(1) so no overflow)
__global__ void k_G(const float* __restrict__ feat, const float* __restrict__ e2,
                    bf16x8* __restrict__ G) {
    int idx = blockIdx.x * blockDim.x + threadIdx.x;
    const int total = B_ * NCH_ * KT_ * 64;
    if (idx >= total) return;
    int lane = idx & 63;
    int t  = (idx >> 6) % KT_;
    int ch = ((idx >> 6) / KT_) % NCH_;
    int b  = idx / (64 * KT_ * NCH_);
    int rg = lane >> 4, col = lane & 15;
    int k  = t * 16 + col;
    int m0 = ch * 32 + rg * 8;
    float vals[8];
    if (k < K_ + H_) {
        int hh, d; bool wonly;
        if (k < K_) { hh = k >> 5; d = k & 31; wonly = false; }
        else        { hh = k - K_; d = 0;      wonly = true;  }
        const float* e2p = e2 + (size_t)(b * H_ + hh) * N_;
        const float* fp  = feat + (size_t)(b * H_ + hh) * N_ * D_ + d;
        #pragma unroll
        for (int j = 0; j < 8; ++j) {
            int m = m0 + j;
            float v = 0.f;
            if (m < N_) {
                float w = __expf(e2p[m]);
                v = wonly ? w : w * fp[(size_t)m * D_];
            }
            vals[j] = v;
        }
    } else {
        #pragma unroll
        for (int j = 0; j < 8; ++j) vals[j] = 0.f;
    }
    union { bf16x8 v; unsigned short u[8]; } o;
    #pragma unroll
    for (int j = 0; j < 8; ++j) o.u[j] = f2bf(vals[j]);
    G[idx] = o.v;
}

// ---- Pass 3 helpers
__device__ __forceinline__ void g2lds16(const void* g, void* l) {
    __builtin_amdgcn_global_load_lds(
        (const __attribute__((address_space(1))) void*)g,
        (__attribute__((address_space(3))) void*)l, 16, 0, 0);
}

// wave w stages its 3 KiB slice (calls 3w..3w+2) of chunk ch; src_ln already has +lane*16
__device__ __forceinline__ void stage3(const char* src_ln, char* dst, int w) {
    int c0 = 3 * w * 1024;
    g2lds16(src_ln + c0,        dst + c0);
    g2lds16(src_ln + c0 + 1024, dst + c0 + 1024);
    g2lds16(src_ln + c0 + 2048, dst + c0 + 2048);
}

__device__ __forceinline__ void loadsetA(const float* __restrict__ arow, int ch, int rg,
                                         f32x4& f0, f32x4& f1) {
    if (ch == NCH_ - 1 && rg == 3) {              // m=3000..3007: out of range
        f0 = (f32x4){0.f, 0.f, 0.f, 0.f};
        f1 = (f32x4){0.f, 0.f, 0.f, 0.f};
    } else {
        const f32x4* p = (const f32x4*)(arow + ch * 32 + rg * 8);
        f0 = p[0]; f1 = p[1];
    }
}

// compute this wave's 3 tiles (tbase..tbase+2) for one chunk, G frags from LDS
__device__ __forceinline__ void compute3(const char* gb, int loff, int tbase,
                                         const f32x4& f0, const f32x4& f1,
                                         f32x4 (&acc)[3]) {
    union { uint32_t u[4]; bf16x8 v; } af;        // bf16 1.0 = 0x3F80, exact 0/1
    af.u[0] = ((f0.x != 0.f) ? 0x3F80u : 0u) | ((f0.y != 0.f) ? 0x3F800000u : 0u);
    af.u[1] = ((f0.z != 0.f) ? 0x3F80u : 0u) | ((f0.w != 0.f) ? 0x3F800000u : 0u);
    af.u[2] = ((f1.x != 0.f) ? 0x3F80u : 0u) | ((f1.y != 0.f) ? 0x3F800000u : 0u);
    af.u[3] = ((f1.z != 0.f) ? 0x3F80u : 0u) | ((f1.w != 0.f) ? 0x3F800000u : 0u);
    const char* p = gb + tbase * 1024 + loff;
    bf16x8 g0 = *(const bf16x8*)(p);
    bf16x8 g1 = *(const bf16x8*)(p + 1024);
    bf16x8 g2 = *(const bf16x8*)(p + 2048);
    acc[0] = __builtin_amdgcn_mfma_f32_16x16x32_bf16(af.v, g0, acc[0], 0, 0, 0);
    acc[1] = __builtin_amdgcn_mfma_f32_16x16x32_bf16(af.v, g1, acc[1], 0, 0, 0);
    acc[2] = __builtin_amdgcn_mfma_f32_16x16x32_bf16(af.v, g2, acc[2], 0, 0, 0);
}

// ---- Pass 3: split-K GEMM, LDS-staged G (global_load_lds double-buffer).
//      Grid = B x NROWT x S_. Block = 3 waves; wave w owns k-tiles {3w,3w+1,3w+2}
//      (no cross-wave reduction). Per chunk: stage next chunk's 9 KiB into LDS,
//      compute current from LDS, __syncthreads (vmcnt drain). Partial -> ws.
__global__ void __launch_bounds__(192, 4) k_main(
        const float* __restrict__ a, const bf16x8* __restrict__ G,
        float* __restrict__ partial) {
    int bid = blockIdx.x;
    int s  = bid % S_;
    int rt = (bid / S_) % NROWT_;
    int b  = bid / (S_ * NROWT_);
    int nbase = rt * 16;
    int w = threadIdx.x >> 6;                     // wave 0..2
    int l = threadIdx.x & 63;
    int rg = l >> 4, col = l & 15;
    int tbase = 3 * w;
    int arow_i = nbase + col;                     // A-frag row = lane&15
    int aclamp = min(arow_i, N_ - 1);
    const float* arow = a + (size_t)(b * N_ + aclamp) * N_;
    const char* Gsrc = (const char*)G + (size_t)b * NCH_ * CHB_ + (size_t)l * 16;

    __shared__ __align__(16) char Gbuf[2][CHB_];  // 18,432 B

    int g0 = (s * NCH_) / S_, g1 = ((s + 1) * NCH_) / S_;

    f32x4 acc[3];
    #pragma unroll
    for (int i = 0; i < 3; ++i) acc[i] = (f32x4){0.f, 0.f, 0.f, 0.f};

    // prologue: stage chunk g0 into buf0, prefetch a(g0)
    f32x4 aA0, aA1, aB0, aB1;
    stage3(Gsrc + (size_t)g0 * CHB_, Gbuf[0], w);
    loadsetA(arow, g0, rg, aA0, aA1);
    __syncthreads();                              // vmcnt(0): buf0 + aA ready

    int ch = g0, buf = 0;
    for (;;) {
        if (ch + 1 < g1) { stage3(Gsrc + (size_t)(ch + 1) * CHB_, Gbuf[buf ^ 1], w);
                           loadsetA(arow, ch + 1, rg, aB0, aB1); }
        compute3(Gbuf[buf], l * 16, tbase, aA0, aA1, acc);
        __syncthreads();                          // next buf ready; current buf free
        buf ^= 1;
        if (++ch >= g1) break;
        if (ch + 1 < g1) { stage3(Gsrc + (size_t)(ch + 1) * CHB_, Gbuf[buf ^ 1], w);
                           loadsetA(arow, ch + 1, rg, aA0, aA1); }
        compute3(Gbuf[buf], l * 16, tbase, aB0, aB1, acc);
        __syncthreads();
        buf ^= 1;
        if (++ch >= g1) break;
    }

    // partial write: wave-owned tiles, coalesced 64-lane stores
    float* pout = partial + (size_t)bid * PT_;
    #pragma unroll
    for (int i = 0; i < 3; ++i) {
        int t = tbase + i;
        #pragma unroll
        for (int r = 0; r < 4; ++r)
            pout[t * 256 + r * 64 + l] = acc[i][r];
    }
}

// ---- Pass 4: sum 8 partials per row-tile + fused epilogue (divide/bias/relu/mask)
__global__ void __launch_bounds__(256) k_red(
        const float* __restrict__ partial, const float* __restrict__ bias,
        const float* __restrict__ nmask, float* __restrict__ out) {
    int rt = blockIdx.x % NROWT_;
    int b  = blockIdx.x / NROWT_;
    int nbase = rt * 16;
    int tid = threadIdx.x;
    __shared__ float sm[PT_];
    const float* pbase = partial + (size_t)((b * NROWT_ + rt) * S_) * PT_;
    #pragma unroll
    for (int k = 0; k < 9; ++k) {
        int flat = tid + k * 256;
        float s = 0.f;
        #pragma unroll
        for (int sp = 0; sp < S_; ++sp) s += pbase[(size_t)sp * PT_ + flat];
        sm[flat] = s;
    }
    __syncthreads();
    #pragma unroll
    for (int k = 0; k < 9; ++k) {
        int flat = tid + k * 256;
        if (flat < 2048) {                        // tiles 0..7 are outputs
            int t4r = flat >> 6;                  // t*4+r
            int t = t4r >> 2, r = t4r & 3;
            int lane = flat & 63;
            int rg = lane >> 4, col = lane & 15;
            int rowi = rg * 4 + r;
            int n = nbase + rowi;
            if (n < N_) {
                int hh = t >> 1;
                int r2 = rowi & 3, rg2 = rowi >> 2;
                float den = sm[(32 + r2) * 64 + (rg2 << 4) + hh];
                float v = (den > 0.f) ? sm[flat] / den : 0.f;
                v += bias[t * 16 + col];
                v = fmaxf(v, 0.f);
                v *= nmask[b * N_ + n];
                out[(size_t)(b * N_ + n) * K_ + t * 16 + col] = v;
            }
        }
    }
}

extern "C" void kernel_launch(void* const* d_in, const int* in_sizes, int n_in,
                              void* d_out, int out_size, void* d_ws, size_t ws_size,
                              hipStream_t stream) {
    const float* h    = (const float*)d_in[0];
    const float* a    = (const float*)d_in[1];
    const float* kern = (const float*)d_in[2];
    // d_in[3] = att_k1: cancels in row-softmax, unused
    const float* ak2  = (const float*)d_in[4];
    const float* bias = (const float*)d_in[5];
    float* out = (float*)d_out;

    char* ws = (char*)d_ws;
    size_t o_feat  = 0;                                   // 768000 f = 3,072,000 B
    size_t o_e2    = o_feat  + 3072000;                   //  24000 f =    96,000 B
    size_t o_nmask = o_e2    + 96000;                     //   6000 f =  24,000 B (pad)
    size_t o_G     = o_nmask + 24064;                     // 108288 * 16 B = 1,732,608 B
    size_t o_part  = o_G     + 1732608;                   // 3008 * 2304 * 4 B = 27,721,728 B
    float*  feat  = (float*)(ws + o_feat);
    float*  e2    = (float*)(ws + o_e2);
    float*  nmask = (float*)(ws + o_nmask);
    bf16x8* G     = (bf16x8*)(ws + o_G);
    float*  part  = (float*)(ws + o_part);

    k_feat<<<dim3(B_ * N_), dim3(128), 0, stream>>>(h, kern, ak2, feat, e2, nmask);
    int gtot = B_ * NCH_ * KT_ * 64;
    k_G   <<<dim3((gtot + 255) / 256), dim3(256), 0, stream>>>(feat, e2, G);
    k_main<<<dim3(B_ * NROWT_ * S_), dim3(192), 0, stream>>>(a, G, part);
    k_red <<<dim3(B_ * NROWT_), dim3(256), 0, stream>>>(part, bias, nmask, out);
}

// Round 8
// 58.283 us; speedup vs baseline: 1.0055x; 1.0055x over previous
//
#include <hip/hip_runtime.h>
#include <hip/hip_bf16.h>
#include <stdint.h>

#define B_ 2
#define N_ 3000
#define F_ 64
#define H_ 4
#define D_ 32
#define K_ 128          // H_*D_ output feature cols
#define KT_ 9           // 9 k-tiles of 16 -> 144 cols (128 feat + 4 denom + 12 pad)
#define NCHP_ 96        // padded m-chunks (3072 m padded; 94 real + 2 zero)
#define BITSW_ 96       // bit-words per adjacency row (padded)
#define NROWT_ 188      // ceil(3000/16) 16-row tiles per batch (for k_red)
#define NRG_ 47         // 64-row groups per batch (k_main)
#define S_ 8            // split-K factor: each split = exactly 12 chunks
#define CHB_ 9216       // bytes per G chunk (9 tiles x 64 lanes x 16B)
#define PTB_ 9216       // floats per partial block (4 waves x 9 tiles x 4 x 64)

typedef short bf16x8 __attribute__((ext_vector_type(8)));
typedef float f32x4  __attribute__((ext_vector_type(4)));

__device__ __forceinline__ unsigned short f2bf(float f) {
    uint32_t x = __float_as_uint(f);
    return (unsigned short)((x + 0x7FFFu + ((x >> 16) & 1u)) >> 16);  // RNE
}

// ---- Pass 0: bit-pack adjacency (a != 0) -> bits[b][n][96 words]; sequential HBM stream
__global__ void k_bits(const float* __restrict__ a, uint32_t* __restrict__ bits) {
    int b = blockIdx.x / N_;
    int n = blockIdx.x % N_;
    const float* row = a + (size_t)(b * N_ + n) * N_;
    uint32_t* brow = bits + (size_t)(b * N_ + n) * BITSW_;
    int wv = threadIdx.x >> 6, lane = threadIdx.x & 63;   // 256 thr = 4 waves
    for (int it = 0; it < 12; ++it) {
        int ig = wv * 12 + it;                            // 64-wide slab index, 0..46 valid
        if (ig < 47) {
            int m = ig * 64 + lane;
            float v = (m < N_) ? row[m] : 0.f;
            unsigned long long bal = __ballot(v != 0.f);
            if (lane == 0)  brow[ig * 2]     = (uint32_t)bal;
            if (lane == 32) brow[ig * 2 + 1] = (uint32_t)(bal >> 32);
        }
    }
    if (threadIdx.x == 0) { brow[94] = 0u; brow[95] = 0u; }  // ws is poisoned; pad words must be 0
}

// ---- Pass 1: feat[b][h][n][d] = h . kernel ; e2[b][h][n] = feat . att_k2 ; node_mask
__global__ void k_feat(const float* __restrict__ hin, const float* __restrict__ kern,
                       const float* __restrict__ ak2,
                       float* __restrict__ feat, float* __restrict__ e2,
                       float* __restrict__ nmask) {
    int b = blockIdx.x / N_;
    int n = blockIdx.x % N_;
    __shared__ float hrow[F_];
    int tid = threadIdx.x;                       // 128 threads: (h = tid>>5, d = tid&31)
    if (tid < F_) hrow[tid] = hin[(size_t)(b * N_ + n) * F_ + tid];
    __syncthreads();
    int hh = tid >> 5, d = tid & 31;
    float acc = 0.f;
    #pragma unroll
    for (int f = 0; f < F_; ++f)
        acc = fmaf(hrow[f], kern[(hh * F_ + f) * D_ + d], acc);
    feat[((size_t)(b * H_ + hh) * N_ + n) * D_ + d] = acc;
    float v = acc * ak2[hh * D_ + d];
    #pragma unroll
    for (int o = 16; o >= 1; o >>= 1) v += __shfl_xor(v, o, 32);
    if (d == 0) e2[(size_t)(b * H_ + hh) * N_ + n] = v;
    unsigned long long bal = __ballot(tid < F_ && hrow[tid & (F_ - 1)] != 0.0f);
    if (tid == 0) nmask[b * N_ + n] = (bal != 0ull) ? 1.0f : 0.0f;
}

// ---- Pass 2: G in MFMA-B-fragment order: G[((b*96+ch)*9+t)*64 + lane] = ushort8
//      lane: rg=lane>>4, col=lane&15 ; element j -> Gmat[m = ch*32+rg*8+j][k = t*16+col]
//      Gmat[m][k<128] = w[h][m]*feat[h][m][d] (h=k>>5,d=k&31); k in 128..131 -> w[k-128][m]; else 0
//      w[h][m] = exp(e2[h][m])  (max-subtraction cancels in the ratio; |e2|~O(1) so no overflow)
__global__ void k_G(const float* __restrict__ feat, const float* __restrict__ e2,
                    bf16x8* __restrict__ G) {
    int idx = blockIdx.x * blockDim.x + threadIdx.x;
    const int total = B_ * NCHP_ * KT_ * 64;
    if (idx >= total) return;
    int lane = idx & 63;
    int t  = (idx >> 6) % KT_;
    int ch = ((idx >> 6) / KT_) % NCHP_;
    int b  = idx / (64 * KT_ * NCHP_);
    int rg = lane >> 4, col = lane & 15;
    int k  = t * 16 + col;
    int m0 = ch * 32 + rg * 8;
    float vals[8];
    if (k < K_ + H_) {
        int hh, d; bool wonly;
        if (k < K_) { hh = k >> 5; d = k & 31; wonly = false; }
        else        { hh = k - K_; d = 0;      wonly = true;  }
        const float* e2p = e2 + (size_t)(b * H_ + hh) * N_;
        const float* fp  = feat + (size_t)(b * H_ + hh) * N_ * D_ + d;
        #pragma unroll
        for (int j = 0; j < 8; ++j) {
            int m = m0 + j;
            float v = 0.f;
            if (m < N_) {
                float w = __expf(e2p[m]);
                v = wonly ? w : w * fp[(size_t)m * D_];
            }
            vals[j] = v;
        }
    } else {
        #pragma unroll
        for (int j = 0; j < 8; ++j) vals[j] = 0.f;
    }
    union { bf16x8 v; unsigned short u[8]; } o;
    #pragma unroll
    for (int j = 0; j < 8; ++j) o.u[j] = f2bf(vals[j]);
    G[idx] = o.v;
}

// ---- Pass 3 helpers
__device__ __forceinline__ void g2lds16(const void* g, void* l) {
    __builtin_amdgcn_global_load_lds(
        (const __attribute__((address_space(1))) void*)g,
        (__attribute__((address_space(3))) void*)l, 16, 0, 0);
}

// 4 waves cooperatively stage one 9216B G chunk: w0{0,1} w1{2,3} w2{4,5} w3{6,7,8}
__device__ __forceinline__ void stage9(const char* src_ln, char* dst, int w) {
    int t0 = 2 * w * 1024;
    g2lds16(src_ln + t0,        dst + t0);
    g2lds16(src_ln + t0 + 1024, dst + t0 + 1024);
    if (w == 3) g2lds16(src_ln + 8 * 1024, dst + 8 * 1024);
}

// all 9 tiles for this wave's 16 rows; gb = Gbuf[cur] + l*16
__device__ __forceinline__ void compute9(const char* gb, uint32_t word, int rg,
                                         f32x4 (&acc)[KT_]) {
    uint32_t mb = (word >> (rg * 8)) & 0xFFu;
    union { uint32_t u[4]; bf16x8 v; } af;        // bf16 1.0 = 0x3F80, exact 0/1
    af.u[0] = ((mb & 1u)   ? 0x3F80u : 0u) | ((mb & 2u)   ? 0x3F800000u : 0u);
    af.u[1] = ((mb & 4u)   ? 0x3F80u : 0u) | ((mb & 8u)   ? 0x3F800000u : 0u);
    af.u[2] = ((mb & 16u)  ? 0x3F80u : 0u) | ((mb & 32u)  ? 0x3F800000u : 0u);
    af.u[3] = ((mb & 64u)  ? 0x3F80u : 0u) | ((mb & 128u) ? 0x3F800000u : 0u);
    #pragma unroll
    for (int t = 0; t < KT_; ++t) {
        bf16x8 g = *(const bf16x8*)(gb + t * 1024);
        acc[t] = __builtin_amdgcn_mfma_f32_16x16x32_bf16(af.v, g, acc[t], 0, 0, 0);
    }
}

// ---- Pass 3: split-K GEMM. Grid = B x NRG x S. Block = 4 waves, 64 rows x 144 cols.
//      Wave w owns rows [rg64*64+w*16, +16), all 9 k-tiles (acc 36 VGPR, no x-wave red).
//      G chunk staged to LDS once per block (shared x4). Bit-words preloaded to regs:
//      inner loop's only VMEM is the G stage. 12 chunks, fully unrolled.
__global__ void __launch_bounds__(256, 4) k_main(
        const uint32_t* __restrict__ bits, const bf16x8* __restrict__ G,
        float* __restrict__ partial) {
    int bid = blockIdx.x;
    int s    = bid % S_;
    int rg64 = (bid / S_) % NRG_;
    int b    = bid / (S_ * NRG_);
    int w = threadIdx.x >> 6;                     // wave 0..3
    int l = threadIdx.x & 63;
    int rg = l >> 4, col = l & 15;
    int row = min(rg64 * 64 + w * 16 + col, N_ - 1);   // A-frag row (clamped; extras discarded)
    const uint32_t* brow = bits + (size_t)(b * N_ + row) * BITSW_ + s * 12;
    const char* Gsrc = (const char*)G + ((size_t)(b * NCHP_ + s * 12)) * CHB_ + (size_t)l * 16;

    __shared__ __align__(16) char Gbuf[2][CHB_];  // 18,432 B

    f32x4 acc[KT_];
    #pragma unroll
    for (int t = 0; t < KT_; ++t) acc[t] = (f32x4){0.f, 0.f, 0.f, 0.f};

    // preload this row's 12 bit-words (L2-resident; once per block)
    uint32_t bw[12];
    #pragma unroll
    for (int i = 0; i < 12; ++i) bw[i] = brow[i];

    // prologue: stage chunk 0
    stage9(Gsrc, Gbuf[0], w);
    __syncthreads();                              // vmcnt(0): buf0 ready

    #pragma unroll
    for (int i = 0; i < 12; ++i) {
        if (i + 1 < 12) stage9(Gsrc + (size_t)(i + 1) * CHB_, Gbuf[(i + 1) & 1], w);
        compute9(Gbuf[i & 1] + l * 16, bw[i], rg, acc);
        __syncthreads();                          // next buf staged; current free
    }

    // partial write: wave-owned rows, coalesced 64-lane stores
    float* pw = partial + (size_t)bid * PTB_ + w * (KT_ * 256);
    #pragma unroll
    for (int t = 0; t < KT_; ++t)
        #pragma unroll
        for (int r = 0; r < 4; ++r)
            pw[t * 256 + r * 64 + l] = acc[t][r];
}

// ---- Pass 4: sum 8 partials per 16-row tile + fused epilogue (divide/bias/relu/mask)
__global__ void __launch_bounds__(256) k_red(
        const float* __restrict__ partial, const float* __restrict__ bias,
        const float* __restrict__ nmask, float* __restrict__ out) {
    int rt = blockIdx.x % NROWT_;                 // 16-row tile 0..187
    int b  = blockIdx.x / NROWT_;
    int nbase = rt * 16;
    int rg64  = rt >> 2;                          // 64-row group
    int wslot = rt & 3;                           // wave slot within k_main block
    int tid = threadIdx.x;
    __shared__ float sm[KT_ * 256];
    const float* pbase = partial + (size_t)((b * NRG_ + rg64) * S_) * PTB_ + wslot * (KT_ * 256);
    #pragma unroll
    for (int k = 0; k < 9; ++k) {
        int flat = tid + k * 256;
        float s = 0.f;
        #pragma unroll
        for (int sp = 0; sp < S_; ++sp) s += pbase[(size_t)sp * PTB_ + flat];
        sm[flat] = s;
    }
    __syncthreads();
    #pragma unroll
    for (int k = 0; k < 9; ++k) {
        int flat = tid + k * 256;
        if (flat < 2048) {                        // tiles 0..7 are outputs
            int t4r = flat >> 6;                  // t*4+r
            int t = t4r >> 2, r = t4r & 3;
            int lane = flat & 63;
            int rg = lane >> 4, col = lane & 15;
            int rowi = rg * 4 + r;
            int n = nbase + rowi;
            if (n < N_) {
                int hh = t >> 1;
                int r2 = rowi & 3, rg2 = rowi >> 2;
                float den = sm[(32 + r2) * 64 + (rg2 << 4) + hh];
                float v = (den > 0.f) ? sm[flat] / den : 0.f;
                v += bias[t * 16 + col];
                v = fmaxf(v, 0.f);
                v *= nmask[b * N_ + n];
                out[(size_t)(b * N_ + n) * K_ + t * 16 + col] = v;
            }
        }
    }
}

extern "C" void kernel_launch(void* const* d_in, const int* in_sizes, int n_in,
                              void* d_out, int out_size, void* d_ws, size_t ws_size,
                              hipStream_t stream) {
    const float* h    = (const float*)d_in[0];
    const float* a    = (const float*)d_in[1];
    const float* kern = (const float*)d_in[2];
    // d_in[3] = att_k1: cancels in row-softmax, unused
    const float* ak2  = (const float*)d_in[4];
    const float* bias = (const float*)d_in[5];
    float* out = (float*)d_out;

    char* ws = (char*)d_ws;
    size_t o_feat  = 0;                                   // 3,072,000 B
    size_t o_e2    = o_feat  + 3072000;                   //    96,000 B
    size_t o_nmask = o_e2    + 96000;                     //    24,064 B (pad)
    size_t o_bits  = o_nmask + 24064;                     // 6000*96*4 = 2,304,000 B
    size_t o_G     = o_bits  + 2304000;                   // 2*96*9216 = 1,769,472 B
    size_t o_part  = o_G     + 1769472;                   // 752*9216*4 = 27,721,728 B
    float*    feat  = (float*)(ws + o_feat);
    float*    e2    = (float*)(ws + o_e2);
    float*    nmask = (float*)(ws + o_nmask);
    uint32_t* bits  = (uint32_t*)(ws + o_bits);
    bf16x8*   G     = (bf16x8*)(ws + o_G);
    float*    part  = (float*)(ws + o_part);

    k_bits<<<dim3(B_ * N_), dim3(256), 0, stream>>>(a, bits);
    k_feat<<<dim3(B_ * N_), dim3(128), 0, stream>>>(h, kern, ak2, feat, e2, nmask);
    int gtot = B_ * NCHP_ * KT_ * 64;
    k_G   <<<dim3((gtot + 255) / 256), dim3(256), 0, stream>>>(feat, e2, G);
    k_main<<<dim3(B_ * NRG_ * S_), dim3(256), 0, stream>>>(bits, G, part);
    k_red <<<dim3(B_ * NROWT_), dim3(256), 0, stream>>>(part, bias, nmask, out);
}